// Round 2
// baseline (370.954 us; speedup 1.0000x reference)
//
#include <hip/hip_runtime.h>

// Problem constants: B=2, N=2048, C=512, H=8, HD=64
// Inputs are fp32 (per reference); intermediates bf16 in ws; output fp32.
typedef __attribute__((ext_vector_type(8))) short bf16x8;
typedef __attribute__((ext_vector_type(4))) float f32x4;

__device__ __forceinline__ float bf2f(unsigned short u) {
  union { unsigned int i; float f; } c; c.i = ((unsigned int)u) << 16; return c.f;
}
__device__ __forceinline__ unsigned short f2bf(float x) {
  union { float f; unsigned int i; } c; c.f = x;
  return (unsigned short)((c.i + 0x7fffu + ((c.i >> 16) & 1u)) >> 16);
}

// Load 8 source elements as 8 packed bf16 (one uint4).
template <typename T> __device__ __forceinline__ uint4 ld8(const T* p);
template <> __device__ __forceinline__ uint4 ld8<unsigned short>(const unsigned short* p) {
  return *(const uint4*)p;
}
template <> __device__ __forceinline__ uint4 ld8<float>(const float* p) {
  const float4 a = *(const float4*)p;
  const float4 b = *(const float4*)(p + 4);
  uint4 r;
  r.x = (unsigned)f2bf(a.x) | ((unsigned)f2bf(a.y) << 16);
  r.y = (unsigned)f2bf(a.z) | ((unsigned)f2bf(a.w) << 16);
  r.z = (unsigned)f2bf(b.x) | ((unsigned)f2bf(b.y) << 16);
  r.w = (unsigned)f2bf(b.z) | ((unsigned)f2bf(b.w) << 16);
  return r;
}

// 64x64 output tile, 256 threads (4 waves x 16-row strips), NT GEMM:
// acc[nt][r] = C[m0 + w*16 + lq*4 + r][cc0 + nt*16 + lm]
// A row-major [M,K] (row stride K), W row-major [Nc,K] (row stride K).
template <int K, typename TA, typename TW>
__device__ __forceinline__ void gemm_mainloop(const TA* __restrict__ Arow,
                                              const TW* __restrict__ Wrow,
                                              short (*As)[72], short (*Ws)[72], f32x4 acc[4]) {
  const int tid = threadIdx.x;
  const int w = tid >> 6, lane = tid & 63, lm = lane & 15, lq = lane >> 4;
#pragma unroll
  for (int nt = 0; nt < 4; ++nt) acc[nt] = (f32x4){0.f, 0.f, 0.f, 0.f};
#pragma unroll 1
  for (int kc = 0; kc < K; kc += 64) {
    __syncthreads();
#pragma unroll
    for (int s = 0; s < 2; ++s) {
      int u = tid + s * 256, row = u >> 3, c8 = (u & 7) * 8;
      *(uint4*)&As[row][c8] = ld8(&Arow[(size_t)row * K + kc + c8]);
      *(uint4*)&Ws[row][c8] = ld8(&Wrow[(size_t)row * K + kc + c8]);
    }
    __syncthreads();
#pragma unroll
    for (int kk = 0; kk < 64; kk += 32) {
      bf16x8 a = *(const bf16x8*)&As[w * 16 + lm][kk + lq * 8];
#pragma unroll
      for (int nt = 0; nt < 4; ++nt) {
        bf16x8 bb = *(const bf16x8*)&Ws[nt * 16 + lm][kk + lq * 8];
        acc[nt] = __builtin_amdgcn_mfma_f32_16x16x32_bf16(a, bb, acc[nt], 0, 0, 0);
      }
    }
  }
}

// qkv = x @ Wqkv^T; scatter to qu=q+u_bias, qv=q+v_bias, k, v in [B,H,N,HD] (bf16)
__global__ __launch_bounds__(256) void k_gemm_qkv(const float* __restrict__ x,
    const float* __restrict__ wqkv, const float* __restrict__ ub,
    const float* __restrict__ vb, unsigned short* __restrict__ qu,
    unsigned short* __restrict__ qv, unsigned short* __restrict__ kg,
    unsigned short* __restrict__ vg) {
  __shared__ short As[64][72], Ws[64][72];
  f32x4 acc[4];
  const int m0 = blockIdx.y * 64, cc0 = blockIdx.x * 64;
  gemm_mainloop<512>(x + (size_t)m0 * 512, wqkv + (size_t)cc0 * 512, As, Ws, acc);
  const int tid = threadIdx.x, w = tid >> 6, lane = tid & 63, lm = lane & 15, lq = lane >> 4;
#pragma unroll
  for (int nt = 0; nt < 4; ++nt) {
    const int cc = cc0 + nt * 16 + lm;
    const int sec = cc >> 9, rem = cc & 511, h = rem >> 6, d = rem & 63;
#pragma unroll
    for (int r = 0; r < 4; ++r) {
      const int m = m0 + w * 16 + lq * 4 + r;
      const int b = m >> 11, n = m & 2047;
      const size_t idx = ((size_t)(b * 8 + h) * 2048 + n) * 64 + d;
      const float val = acc[nt][r];
      if (sec == 0) {
        qu[idx] = f2bf(val + ub[rem]);
        qv[idx] = f2bf(val + vb[rem]);
      } else if (sec == 1) {
        kg[idx] = f2bf(val);
      } else {
        vg[idx] = f2bf(val);
      }
    }
  }
}

// pos = pos_embedding @ Wpos^T -> [B,H,N,HD] (bf16)
__global__ __launch_bounds__(256) void k_gemm_pos(const float* __restrict__ pe,
    const float* __restrict__ wpos, unsigned short* __restrict__ pos) {
  __shared__ short As[64][72], Ws[64][72];
  f32x4 acc[4];
  const int m0 = blockIdx.y * 64, cc0 = blockIdx.x * 64;
  gemm_mainloop<512>(pe + (size_t)m0 * 512, wpos + (size_t)cc0 * 512, As, Ws, acc);
  const int tid = threadIdx.x, w = tid >> 6, lane = tid & 63, lm = lane & 15, lq = lane >> 4;
#pragma unroll
  for (int nt = 0; nt < 4; ++nt) {
    const int cc = cc0 + nt * 16 + lm, h = cc >> 6, d = cc & 63;
#pragma unroll
    for (int r = 0; r < 4; ++r) {
      const int m = m0 + w * 16 + lq * 4 + r, b = m >> 11, n = m & 2047;
      pos[((size_t)(b * 8 + h) * 2048 + n) * 64 + d] = f2bf(acc[nt][r]);
    }
  }
}

// vt[b,h,d,n] = v[b,h,n,d]  (so PV B-fragments are contiguous 16B LDS reads)
__global__ __launch_bounds__(256) void k_transpose_v(const unsigned short* __restrict__ vg,
                                                     unsigned short* __restrict__ vt) {
  __shared__ short T[64][72];
  const int tid = threadIdx.x, bhid = blockIdx.y, n0 = blockIdx.x * 64;
#pragma unroll
  for (int s = 0; s < 2; ++s) {
    int u = tid + s * 256, row = u >> 3, c8 = (u & 7) * 8;
    *(uint4*)&T[row][c8] = *(const uint4*)&vg[((size_t)bhid * 2048 + n0 + row) * 64 + c8];
  }
  __syncthreads();
#pragma unroll
  for (int s = 0; s < 2; ++s) {
    int u = tid + s * 256, d = u >> 3, n8 = (u & 7) * 8;
    alignas(16) unsigned short tmp[8];
#pragma unroll
    for (int jj = 0; jj < 8; ++jj) tmp[jj] = (unsigned short)T[n8 + jj][d];
    *(uint4*)&vt[((size_t)bhid * 64 + d) * 2048 + n0 + n8] = *(const uint4*)tmp;
  }
}

// ps[bh,i,e] = (q_i + v_bias) . pos_e   (per (b,h): M=2048, Nc=2048, K=64)
__global__ __launch_bounds__(256) void k_gemm_ps(const unsigned short* __restrict__ qv,
    const unsigned short* __restrict__ pos, unsigned short* __restrict__ ps) {
  __shared__ short As[64][72], Ws[64][72];
  f32x4 acc[4];
  const int bh = blockIdx.z;
  gemm_mainloop<64>(qv + ((size_t)bh * 2048 + blockIdx.y * 64) * 64,
                    pos + ((size_t)bh * 2048 + blockIdx.x * 64) * 64, As, Ws, acc);
  const int tid = threadIdx.x, w = tid >> 6, lane = tid & 63, lm = lane & 15, lq = lane >> 4;
#pragma unroll
  for (int nt = 0; nt < 4; ++nt) {
    const int e = blockIdx.x * 64 + nt * 16 + lm;
#pragma unroll
    for (int r = 0; r < 4; ++r) {
      const int i = blockIdx.y * 64 + w * 16 + lq * 4 + r;
      ps[((size_t)bh * 2048 + i) * 2048 + e] = f2bf(acc[nt][r]);
    }
  }
}

// Flash attention over j-tiles of 64: content MFMA + gathered shifted-ps +
// online softmax + P@V (P via in-wave LDS C-layout -> A-layout round trip).
__global__ __launch_bounds__(256) void k_flash(const unsigned short* __restrict__ qu,
    const unsigned short* __restrict__ kg, const unsigned short* __restrict__ vt,
    const unsigned short* __restrict__ ps, unsigned short* __restrict__ og) {
  __shared__ short Ks[64][72], Vs[64][72], Ps[4][16][72];
  const int tid = threadIdx.x, w = tid >> 6, lane = tid & 63, lm = lane & 15, lq = lane >> 4;
  const int h = blockIdx.y, b = blockIdx.z;
  const int iw = blockIdx.x * 64 + w * 16;
  const size_t bh = (size_t)(b * 8 + h);
  // A-frags for QK^T: lane holds Qu[iw + lm][lq*8 + j] for k-chunks 0,32
  const bf16x8 au0 = *(const bf16x8*)&qu[(bh * 2048 + iw + lm) * 64 + lq * 8];
  const bf16x8 au1 = *(const bf16x8*)&qu[(bh * 2048 + iw + lm) * 64 + 32 + lq * 8];
  const unsigned short* psb = ps + bh * (size_t)2048 * 2048;
  float m_run[4], l_run[4];
  f32x4 oacc[4];
#pragma unroll
  for (int r = 0; r < 4; ++r) { m_run[r] = -1e30f; l_run[r] = 0.f; }
#pragma unroll
  for (int dt = 0; dt < 4; ++dt) oacc[dt] = (f32x4){0.f, 0.f, 0.f, 0.f};
  for (int j0 = 0; j0 < 2048; j0 += 64) {
    __syncthreads();
#pragma unroll
    for (int s = 0; s < 2; ++s) {
      int u = tid + s * 256, row = u >> 3, c8 = (u & 7) * 8;
      *(uint4*)&Ks[row][c8] = *(const uint4*)&kg[(bh * 2048 + j0 + row) * 64 + c8];
      *(uint4*)&Vs[row][c8] = *(const uint4*)&vt[(bh * 64 + row) * 2048 + j0 + c8];
    }
    __syncthreads();
    float lgt[4][4];
#pragma unroll
    for (int nt = 0; nt < 4; ++nt) {
      bf16x8 b0 = *(const bf16x8*)&Ks[nt * 16 + lm][lq * 8];
      bf16x8 b1 = *(const bf16x8*)&Ks[nt * 16 + lm][32 + lq * 8];
      f32x4 c = __builtin_amdgcn_mfma_f32_16x16x32_bf16(au0, b0, (f32x4){0.f,0.f,0.f,0.f}, 0, 0, 0);
      c = __builtin_amdgcn_mfma_f32_16x16x32_bf16(au1, b1, c, 0, 0, 0);
      const int j = j0 + nt * 16 + lm;  // C-layout: col = lm
#pragma unroll
      for (int r = 0; r < 4; ++r) {
        const int i = iw + lq * 4 + r;  // C-layout: row = lq*4 + r
        // relative shift: ps[i, N-1-i+j] if j<=i ; 0 if j==i+1 ; ps[i+1, j-i-2] if j>=i+2
        float pv = 0.f;
        if (j <= i)          pv = bf2f(psb[(size_t)i * 2048 + (2047 - i + j)]);
        else if (j >= i + 2) pv = bf2f(psb[(size_t)(i + 1) * 2048 + (j - i - 2)]);
        lgt[nt][r] = (c[r] + pv) * 0.125f;
      }
    }
#pragma unroll
    for (int r = 0; r < 4; ++r) {
      float rmax = fmaxf(fmaxf(lgt[0][r], lgt[1][r]), fmaxf(lgt[2][r], lgt[3][r]));
#pragma unroll
      for (int off = 1; off < 16; off <<= 1) rmax = fmaxf(rmax, __shfl_xor(rmax, off, 64));
      const float mnew = fmaxf(m_run[r], rmax);
      const float alpha = exp2f((m_run[r] - mnew) * 1.4426950408889634f);
      float p[4], psum = 0.f;
#pragma unroll
      for (int nt = 0; nt < 4; ++nt) {
        p[nt] = exp2f((lgt[nt][r] - mnew) * 1.4426950408889634f);
        psum += p[nt];
      }
#pragma unroll
      for (int off = 1; off < 16; off <<= 1) psum += __shfl_xor(psum, off, 64);
      l_run[r] = l_run[r] * alpha + psum;
      m_run[r] = mnew;
#pragma unroll
      for (int dt = 0; dt < 4; ++dt) oacc[dt][r] *= alpha;
#pragma unroll
      for (int nt = 0; nt < 4; ++nt) Ps[w][lq * 4 + r][nt * 16 + lm] = (short)f2bf(p[nt]);
    }
    // P: C-layout -> A-layout via per-wave LDS (in-order DS pipe, same wave)
    bf16x8 p0 = *(const bf16x8*)&Ps[w][lm][lq * 8];
    bf16x8 p1 = *(const bf16x8*)&Ps[w][lm][32 + lq * 8];
#pragma unroll
    for (int dt = 0; dt < 4; ++dt) {
      bf16x8 v0 = *(const bf16x8*)&Vs[dt * 16 + lm][lq * 8];
      bf16x8 v1 = *(const bf16x8*)&Vs[dt * 16 + lm][32 + lq * 8];
      oacc[dt] = __builtin_amdgcn_mfma_f32_16x16x32_bf16(p0, v0, oacc[dt], 0, 0, 0);
      oacc[dt] = __builtin_amdgcn_mfma_f32_16x16x32_bf16(p1, v1, oacc[dt], 0, 0, 0);
    }
  }
#pragma unroll
  for (int r = 0; r < 4; ++r) {
    const float inv = 1.f / l_run[r];
    const int i = iw + lq * 4 + r;
#pragma unroll
    for (int dt = 0; dt < 4; ++dt)
      og[((size_t)b * 2048 + i) * 512 + h * 64 + dt * 16 + lm] = f2bf(oacc[dt][r] * inv);
  }
}

// out = O @ Wproj^T + bproj   (og bf16, wproj/bproj/out fp32)
__global__ __launch_bounds__(256) void k_gemm_proj(const unsigned short* __restrict__ og,
    const float* __restrict__ wproj, const float* __restrict__ bproj,
    float* __restrict__ out) {
  __shared__ short As[64][72], Ws[64][72];
  f32x4 acc[4];
  const int m0 = blockIdx.y * 64, cc0 = blockIdx.x * 64;
  gemm_mainloop<512>(og + (size_t)m0 * 512, wproj + (size_t)cc0 * 512, As, Ws, acc);
  const int tid = threadIdx.x, w = tid >> 6, lane = tid & 63, lm = lane & 15, lq = lane >> 4;
#pragma unroll
  for (int nt = 0; nt < 4; ++nt) {
    const int cc = cc0 + nt * 16 + lm;
    const float bias = bproj[cc];
#pragma unroll
    for (int r = 0; r < 4; ++r) {
      const int m = m0 + w * 16 + lq * 4 + r;
      out[(size_t)m * 512 + cc] = acc[nt][r] + bias;
    }
  }
}

extern "C" void kernel_launch(void* const* d_in, const int* in_sizes, int n_in,
                              void* d_out, int out_size, void* d_ws, size_t ws_size,
                              hipStream_t stream) {
  const float* x     = (const float*)d_in[0];
  const float* pe    = (const float*)d_in[1];
  const float* wqkv  = (const float*)d_in[2];
  const float* wpos  = (const float*)d_in[3];
  const float* ub    = (const float*)d_in[4];
  const float* vb    = (const float*)d_in[5];
  const float* wproj = (const float*)d_in[6];
  const float* bproj = (const float*)d_in[7];
  float* out = (float*)d_out;
  unsigned short* ws = (unsigned short*)d_ws;

  const size_t SZ = (size_t)2 * 8 * 2048 * 64;  // one [B,H,N,HD] buffer (2M elems)
  unsigned short* qu  = ws;
  unsigned short* qv  = qu + SZ;
  unsigned short* kg  = qv + SZ;
  unsigned short* vg  = kg + SZ;
  unsigned short* vt  = vg + SZ;
  unsigned short* pos = vt + SZ;
  unsigned short* og  = pos + SZ;
  unsigned short* ps  = og + SZ;  // [B*H, N, N] = 64M elems (128 MB)

  dim3 blk(256);
  hipLaunchKernelGGL(k_gemm_qkv,   dim3(24, 64),     blk, 0, stream, x, wqkv, ub, vb, qu, qv, kg, vg);
  hipLaunchKernelGGL(k_gemm_pos,   dim3(8, 64),      blk, 0, stream, pe, wpos, pos);
  hipLaunchKernelGGL(k_transpose_v,dim3(32, 16),     blk, 0, stream, vg, vt);
  hipLaunchKernelGGL(k_gemm_ps,    dim3(32, 32, 16), blk, 0, stream, qv, pos, ps);
  hipLaunchKernelGGL(k_flash,      dim3(32, 8, 2),   blk, 0, stream, qu, kg, vt, ps, og);
  hipLaunchKernelGGL(k_gemm_proj,  dim3(8, 64),      blk, 0, stream, og, wproj, bproj, out);
}